// Round 1
// baseline (418.365 us; speedup 1.0000x reference)
//
#include <hip/hip_runtime.h>

// EGNN fused layer, MI355X gfx950.
// out[0 : 50000*64)          = h + segment_sum(node messages, dst)
// out[50000*64 : +50000*3)   = x + segment_sum(coord updates, dst)
//
// Design: bf16 MFMA (16x16x32) for the two big per-edge GEMMs (share m_input),
// weights as B-frags in registers (loaded once per persistent block),
// m_input + hidden tiles staged in LDS, atomicAdd scatter epilogue.

#define NN 50000
#define NE 800000
#define NDIM 64
#define HDIM 128
#define EDIM 32
#define NTILES (NE / 64)      // 12500, exact
#define MSTRIDE 168           // m_input LDS row stride (ushorts): 160 + 8 pad
#define HSTRIDE 136           // hidden LDS row stride: 128 + 8 pad
#define NH (NN * NDIM)        // 3,200,000
#define NX (NN * 3)           // 150,000

typedef __bf16 bf16x8 __attribute__((ext_vector_type(8)));
typedef float f32x4 __attribute__((ext_vector_type(4)));
typedef unsigned short ushort8 __attribute__((ext_vector_type(8)));
typedef unsigned short ushort4v __attribute__((ext_vector_type(4)));

__device__ __forceinline__ unsigned short f2bf(float f) {
    union { float f; unsigned int u; } c; c.f = f;
    unsigned int r = c.u + 0x7fffu + ((c.u >> 16) & 1u);   // RNE
    return (unsigned short)(r >> 16);
}
__device__ __forceinline__ float bf2f(unsigned short u) {
    union { unsigned int u; float f; } c; c.u = ((unsigned int)u) << 16;
    return c.f;
}
__device__ __forceinline__ float silu(float v) { return v / (1.0f + __expf(-v)); }

__device__ __forceinline__ bf16x8 ld_frag(const unsigned short* p) {
    union { ushort8 u; bf16x8 v; } c;
    c.u = *(const ushort8*)p;
    return c.v;
}
__device__ __forceinline__ bf16x8 mk_frag(const unsigned short* u) {
    union { ushort8 uu; bf16x8 v; } c;
#pragma unroll
    for (int j = 0; j < 8; ++j) c.uu[j] = u[j];
    return c.v;
}

__global__ void init_out(const float* __restrict__ h, const float* __restrict__ x,
                         float* __restrict__ out) {
    int i = blockIdx.x * 256 + threadIdx.x;
    if (i < NH) out[i] = h[i];
    else if (i < NH + NX) out[i] = x[i - NH];
}

__global__ __launch_bounds__(256, 2) void egnn_edges(
    const float* __restrict__ h, const float* __restrict__ x,
    const int* __restrict__ srcg, const int* __restrict__ dstg,
    const float* __restrict__ dist,
    const float* __restrict__ We1, const float* __restrict__ be1,
    const float* __restrict__ We2, const float* __restrict__ be2,
    const float* __restrict__ Wn1, const float* __restrict__ bn1,
    const float* __restrict__ Wn2, const float* __restrict__ bn2,
    const float* __restrict__ Wc1, const float* __restrict__ bc1,
    const float* __restrict__ Wc2,
    float* __restrict__ outh, float* __restrict__ outx) {

    __shared__ __align__(16) unsigned short mlds[64 * MSTRIDE];  // m_input tile bf16
    __shared__ __align__(16) unsigned short hl[64 * HSTRIDE];    // hidden tile bf16
    __shared__ int src_l[64];
    __shared__ int dst_l[64];
    __shared__ float dist_l[64];
    __shared__ float we1_l[32], be1_l[32], be2_l[32];
    __shared__ float we2_l[32 * 32];
    __shared__ float wc2_l[128];
    __shared__ float part_l[256];

    const int tid  = threadIdx.x;
    const int w    = tid >> 6;        // wave 0..3
    const int lane = tid & 63;
    const int l15  = lane & 15;
    const int quad = lane >> 4;

    // ---- one-time: small weights to LDS ----
    if (tid < 32) { we1_l[tid] = We1[tid]; be1_l[tid] = be1[tid]; be2_l[tid] = be2[tid]; }
    if (tid < 128) wc2_l[tid] = Wc2[tid];
    for (int i = tid; i < 1024; i += 256) we2_l[i] = We2[i];

    // ---- one-time: B-fragments to registers ----
    // GEMM1: wave w covers hidden cols [w*32, w*32+32) via 2 N-tiles of 16.
    // B layout (32x16 tile): n = lane&15, k = quad*8 + j
    bf16x8 wn1f[5][2], wc1f[5][2];
#pragma unroll
    for (int kc = 0; kc < 5; ++kc) {
#pragma unroll
        for (int nt = 0; nt < 2; ++nt) {
            unsigned short un[8], uc[8];
            const int n = w * 32 + nt * 16 + l15;
#pragma unroll
            for (int j = 0; j < 8; ++j) {
                const int k = kc * 32 + quad * 8 + j;
                un[j] = f2bf(Wn1[k * HDIM + n]);
                uc[j] = f2bf(Wc1[k * HDIM + n]);
            }
            wn1f[kc][nt] = mk_frag(un);
            wc1f[kc][nt] = mk_frag(uc);
        }
    }
    // GEMM2 (node): wave w covers out cols [w*16, w*16+16)
    bf16x8 wn2f[4];
#pragma unroll
    for (int kc = 0; kc < 4; ++kc) {
        unsigned short u[8];
        const int n = w * 16 + l15;
#pragma unroll
        for (int j = 0; j < 8; ++j) {
            const int k = kc * 32 + quad * 8 + j;
            u[j] = f2bf(Wn2[k * NDIM + n]);
        }
        wn2f[kc] = mk_frag(u);
    }
    const float biasN0 = bn1[w * 32 + l15];
    const float biasN1 = bn1[w * 32 + 16 + l15];
    const float biasC0 = bc1[w * 32 + l15];
    const float biasC1 = bc1[w * 32 + 16 + l15];
    const float bias2v = bn2[w * 16 + l15];

    for (int tile = blockIdx.x; tile < NTILES; tile += gridDim.x) {
        __syncthreads();   // protect LDS reuse from previous iteration

        if (tid < 64) {
            const int e = tile * 64 + tid;
            src_l[tid] = srcg[e];
            dst_l[tid] = dstg[e];
            dist_l[tid] = dist[e];
        }
        __syncthreads();

        // ---- stage m_input = [h[src] | h[dst] | e] as bf16 ----
        {
            const int c4 = tid & 15, sub = tid >> 4;
#pragma unroll
            for (int it = 0; it < 4; ++it) {
                const int el = sub + it * 16;
                const float4 hs = *(const float4*)(h + (size_t)src_l[el] * NDIM + c4 * 4);
                const float4 hd = *(const float4*)(h + (size_t)dst_l[el] * NDIM + c4 * 4);
                ushort4v us = { f2bf(hs.x), f2bf(hs.y), f2bf(hs.z), f2bf(hs.w) };
                ushort4v ud = { f2bf(hd.x), f2bf(hd.y), f2bf(hd.z), f2bf(hd.w) };
                *(ushort4v*)&mlds[el * MSTRIDE + c4 * 4] = us;
                *(ushort4v*)&mlds[el * MSTRIDE + 64 + c4 * 4] = ud;
            }
        }
        // ---- edge MLP: e = silu(d*We1+be1) @ We2 + be2  (8 outputs/thread) ----
        {
            const int el = tid >> 2, part = tid & 3;
            const float dv = dist_l[el];
            float o[8];
#pragma unroll
            for (int j = 0; j < 8; ++j) o[j] = be2_l[part * 8 + j];
#pragma unroll
            for (int k = 0; k < 32; ++k) {
                const float sk = silu(dv * we1_l[k] + be1_l[k]);
#pragma unroll
                for (int j = 0; j < 8; ++j) o[j] += sk * we2_l[k * 32 + part * 8 + j];
            }
            ushort4v a = { f2bf(o[0]), f2bf(o[1]), f2bf(o[2]), f2bf(o[3]) };
            ushort4v b = { f2bf(o[4]), f2bf(o[5]), f2bf(o[6]), f2bf(o[7]) };
            *(ushort4v*)&mlds[el * MSTRIDE + 128 + part * 8] = a;
            *(ushort4v*)&mlds[el * MSTRIDE + 128 + part * 8 + 4] = b;
        }
        __syncthreads();

        // ---- GEMM1: [64x160] @ {Wn1, Wc1} -> hidden [64x128] per path ----
        f32x4 accN[4][2], accC[4][2];
#pragma unroll
        for (int mt = 0; mt < 4; ++mt) {
            accN[mt][0] = (f32x4){biasN0, biasN0, biasN0, biasN0};
            accN[mt][1] = (f32x4){biasN1, biasN1, biasN1, biasN1};
            accC[mt][0] = (f32x4){biasC0, biasC0, biasC0, biasC0};
            accC[mt][1] = (f32x4){biasC1, biasC1, biasC1, biasC1};
        }
#pragma unroll
        for (int kc = 0; kc < 5; ++kc) {
            bf16x8 af[4];
#pragma unroll
            for (int mt = 0; mt < 4; ++mt)
                af[mt] = ld_frag(&mlds[(mt * 16 + l15) * MSTRIDE + kc * 32 + quad * 8]);
#pragma unroll
            for (int mt = 0; mt < 4; ++mt) {
#pragma unroll
                for (int nt = 0; nt < 2; ++nt) {
                    accN[mt][nt] = __builtin_amdgcn_mfma_f32_16x16x32_bf16(
                        af[mt], wn1f[kc][nt], accN[mt][nt], 0, 0, 0);
                    accC[mt][nt] = __builtin_amdgcn_mfma_f32_16x16x32_bf16(
                        af[mt], wc1f[kc][nt], accC[mt][nt], 0, 0, 0);
                }
            }
        }

        // ---- node path: silu -> LDS (C-layout -> A-layout round trip) ----
#pragma unroll
        for (int mt = 0; mt < 4; ++mt)
#pragma unroll
            for (int nt = 0; nt < 2; ++nt)
#pragma unroll
                for (int r = 0; r < 4; ++r)
                    hl[(mt * 16 + quad * 4 + r) * HSTRIDE + w * 32 + nt * 16 + l15] =
                        f2bf(silu(accN[mt][nt][r]));
        __syncthreads();

        // ---- GEMM2 node: [64x128] @ Wn2 -> m [64x64] ----
        f32x4 acc2[4];
#pragma unroll
        for (int mt = 0; mt < 4; ++mt) acc2[mt] = (f32x4){bias2v, bias2v, bias2v, bias2v};
#pragma unroll
        for (int kc = 0; kc < 4; ++kc) {
#pragma unroll
            for (int mt = 0; mt < 4; ++mt) {
                bf16x8 a2 = ld_frag(&hl[(mt * 16 + l15) * HSTRIDE + kc * 32 + quad * 8]);
                acc2[mt] = __builtin_amdgcn_mfma_f32_16x16x32_bf16(a2, wn2f[kc], acc2[mt], 0, 0, 0);
            }
        }
        // scatter node messages
#pragma unroll
        for (int mt = 0; mt < 4; ++mt) {
#pragma unroll
            for (int r = 0; r < 4; ++r) {
                const int el = mt * 16 + quad * 4 + r;
                atomicAdd(outh + (size_t)dst_l[el] * NDIM + w * 16 + l15, acc2[mt][r]);
            }
        }
        __syncthreads();   // all GEMM2 reads of hl done

        // ---- coord path: silu -> LDS ----
#pragma unroll
        for (int mt = 0; mt < 4; ++mt)
#pragma unroll
            for (int nt = 0; nt < 2; ++nt)
#pragma unroll
                for (int r = 0; r < 4; ++r)
                    hl[(mt * 16 + quad * 4 + r) * HSTRIDE + w * 32 + nt * 16 + l15] =
                        f2bf(silu(accC[mt][nt][r]));
        __syncthreads();

        // ---- coord matvec: hidden_c @ Wc2, 4 partials per edge ----
        {
            const int el = tid & 63, part = tid >> 6;
            float s = 0.0f;
#pragma unroll
            for (int k = 0; k < 32; ++k) {
                const int kk = part * 32 + k;
                s += bf2f(hl[el * HSTRIDE + kk]) * wc2_l[kk];
            }
            part_l[part * 64 + el] = s;
        }
        __syncthreads();

        if (tid < 64) {
            const float cw = part_l[tid] + part_l[64 + tid] + part_l[128 + tid] + part_l[192 + tid];
            const int sn = src_l[tid], dn = dst_l[tid];
            const float dx = x[sn * 3 + 0] - x[dn * 3 + 0];
            const float dy = x[sn * 3 + 1] - x[dn * 3 + 1];
            const float dz = x[sn * 3 + 2] - x[dn * 3 + 2];
            float len = sqrtf(dx * dx + dy * dy + dz * dz);
            len = fmaxf(len, 1e-8f);
            const float f = cw / len;
            atomicAdd(outx + (size_t)dn * 3 + 0, f * dx);
            atomicAdd(outx + (size_t)dn * 3 + 1, f * dy);
            atomicAdd(outx + (size_t)dn * 3 + 2, f * dz);
        }
    }
}

extern "C" void kernel_launch(void* const* d_in, const int* in_sizes, int n_in,
                              void* d_out, int out_size, void* d_ws, size_t ws_size,
                              hipStream_t stream) {
    const float* h    = (const float*)d_in[0];
    const float* x    = (const float*)d_in[1];
    const int*   ei   = (const int*)d_in[2];     // int32 (jax x64 disabled), [2, NE]
    const float* dist = (const float*)d_in[3];
    const float* We1  = (const float*)d_in[4];
    const float* be1  = (const float*)d_in[5];
    const float* We2  = (const float*)d_in[6];
    const float* be2  = (const float*)d_in[7];
    const float* Wn1  = (const float*)d_in[8];
    const float* bn1  = (const float*)d_in[9];
    const float* Wn2  = (const float*)d_in[10];
    const float* bn2  = (const float*)d_in[11];
    const float* Wc1  = (const float*)d_in[12];
    const float* bc1  = (const float*)d_in[13];
    const float* Wc2  = (const float*)d_in[14];

    float* outh = (float*)d_out;
    float* outx = outh + (size_t)NH;

    init_out<<<(NH + NX + 255) / 256, 256, 0, stream>>>(h, x, (float*)d_out);
    egnn_edges<<<512, 256, 0, stream>>>(h, x, ei, ei + NE, dist,
                                        We1, be1, We2, be2,
                                        Wn1, bn1, Wn2, bn2,
                                        Wc1, bc1, Wc2,
                                        outh, outx);
}